// Round 3
// baseline (530.572 us; speedup 1.0000x reference)
//
#include <hip/hip_runtime.h>
#include <stdint.h>

// ---------------------------------------------------------------------------
// MultiHeadAttention: out = proj(attn(qkv_proj(query)))
// B=4 S=2048 E=1024 H=16 HD=64.  scale = 1/sqrt(E) = 1/32.
// cvt(fp32->bf16) -> GEMM1(bias, bf16 out) -> flash-attn -> GEMM2(bias, f32 out)
// ---------------------------------------------------------------------------

typedef __bf16 bf16;
typedef __bf16 bf16x8 __attribute__((ext_vector_type(8)));
typedef __bf16 bf16x4 __attribute__((ext_vector_type(4)));
typedef float  f32x4  __attribute__((ext_vector_type(4)));

#define MFMA16(a, b, c) __builtin_amdgcn_mfma_f32_16x16x32_bf16((a), (b), (c), 0, 0, 0)

__device__ __forceinline__ void gload16(const void* g, void* l) {
  __builtin_amdgcn_global_load_lds(
      (const __attribute__((address_space(1))) void*)g,
      (__attribute__((address_space(3))) void*)l, 16, 0, 0);
}

__device__ __forceinline__ uint32_t lds_off(const void* p) {
  return (uint32_t)(uintptr_t)(__attribute__((address_space(3))) const void*)p;
}

// hardware transpose read, natural-b64 addressing: lane supplies its own
// 8-byte-chunk address within a [4][16]-bf16 subtile; HW returns the COLUMN
// (addr>>3)&15 of that subtile: data elem j = (addr>>7)*64 + ((addr>>3)&15) + j*16.
__device__ __forceinline__ bf16x4 tr16(uint32_t off) {
  bf16x4 d;
  asm volatile("ds_read_b64_tr_b16 %0, %1" : "=&v"(d) : "v"(off));
  return d;
}

// ---------------------------------------------------------------- convert ---
__global__ __launch_bounds__(256) void cvt_f32_bf16(const float* __restrict__ in,
                                                    bf16* __restrict__ out, int n4) {
  int i = blockIdx.x * 256 + threadIdx.x;
  if (i >= n4) return;
  const float4 v = ((const float4*)in)[i];
  bf16x4 o;
  o[0] = (bf16)v.x; o[1] = (bf16)v.y; o[2] = (bf16)v.z; o[3] = (bf16)v.w;
  ((bf16x4*)out)[i] = o;
}

// ------------------------------------------------------------------- GEMM ---
// C[M][N] = A[M][K] @ Bt[N][K]^T + bias[N].  m97 structure (unchanged).
template <typename OutT>
__global__ __launch_bounds__(256, 2) void gemm_bt(const bf16* __restrict__ A,
                                                  const bf16* __restrict__ Bt,
                                                  const float* __restrict__ bias,
                                                  OutT* __restrict__ C,
                                                  int M, int N, int K) {
  __shared__ bf16 As[128 * 32];
  __shared__ bf16 Bs[128 * 32];
  const int tid = threadIdx.x;
  const int lane = tid & 63, wid = tid >> 6;
  const int l15 = lane & 15, lg = lane >> 4;
  const int wr = wid >> 1, wc = wid & 1;
  const int row0 = blockIdx.y * 128, col0 = blockIdx.x * 128;

  f32x4 acc[4][4];
#pragma unroll
  for (int m = 0; m < 4; ++m)
#pragma unroll
    for (int n = 0; n < 4; ++n) acc[m][n] = (f32x4){0.f, 0.f, 0.f, 0.f};

  for (int k0 = 0; k0 < K; k0 += 32) {
    __syncthreads();
#pragma unroll
    for (int j = 0; j < 2; ++j) {
      const int c = j * 256 + tid;
      const int r = c >> 2, cb = (c & 3) << 4;
      gload16((const char*)(A + (size_t)(row0 + r) * K + k0) + cb, (char*)As + c * 16);
      gload16((const char*)(Bt + (size_t)(col0 + r) * K + k0) + cb, (char*)Bs + c * 16);
    }
    __syncthreads();

    bf16x8 af[4], bfr[4];
#pragma unroll
    for (int m = 0; m < 4; ++m)
      af[m] = *(const bf16x8*)(As + ((wr * 64 + m * 16 + l15) << 5) + lg * 8);
#pragma unroll
    for (int n = 0; n < 4; ++n)
      bfr[n] = *(const bf16x8*)(Bs + ((wc * 64 + n * 16 + l15) << 5) + lg * 8);
#pragma unroll
    for (int m = 0; m < 4; ++m)
#pragma unroll
      for (int n = 0; n < 4; ++n) acc[m][n] = MFMA16(af[m], bfr[n], acc[m][n]);
  }

#pragma unroll
  for (int m = 0; m < 4; ++m) {
    const int grow0 = row0 + wr * 64 + m * 16 + lg * 4;
#pragma unroll
    for (int n = 0; n < 4; ++n) {
      const int gcol = col0 + wc * 64 + n * 16 + l15;
      const float bv = bias[gcol];
#pragma unroll
      for (int i = 0; i < 4; ++i)
        C[(size_t)(grow0 + i) * N + gcol] = (OutT)(acc[m][n][i] + bv);
    }
  }
}

// -------------------------------------------------------------- attention ---
// grid (S/128, H, B); block 256 = 4 waves, each wave owns 32 q-rows (2 frags).
// K tile [64key][64d] in LDS, XOR-swizzled via pre-swizzled gload source.
// V tile subtiled [kb=16][db=4][4key][16d] via gload (linear), read with
// ds_read_b64_tr_b16 (HW transpose, natural-b64 per-lane addressing).
__global__ __launch_bounds__(256, 4) void attn_fwd(const bf16* __restrict__ qkv,
                                                   bf16* __restrict__ aout) {
  __shared__ bf16 Ks[64 * 64];
  __shared__ bf16 Vs[64 * 64];
  __shared__ bf16 Ps[4][32 * 64];

  const int qblk = blockIdx.x, h = blockIdx.y, b = blockIdx.z;
  const int tid = threadIdx.x, wid = tid >> 6, lane = tid & 63;
  const int l15 = lane & 15, lg = lane >> 4;
  const bf16* qbase = qkv + (size_t)b * 2048 * 3072;
  constexpr float SC = 0.045084220f;  // (1/32) * log2(e)

  // Q fragments: rows qblk*128 + wid*32 + m*16 + l15, k = kk*32 + lg*8
  bf16x8 qf[2][2];
  {
    const bf16* qp = qbase + (size_t)(qblk * 128 + wid * 32 + l15) * 3072 + h * 64 + lg * 8;
    qf[0][0] = *(const bf16x8*)(qp);
    qf[0][1] = *(const bf16x8*)(qp + 32);
    qf[1][0] = *(const bf16x8*)(qp + 16 * 3072);
    qf[1][1] = *(const bf16x8*)(qp + 16 * 3072 + 32);
  }

  // staging source/dest: 2 K-chunks + 2 V-chunks per thread per tile
  const char* ksrc[2]; const char* vsrc[2];
  char* kdst[2]; char* vdst[2];
#pragma unroll
  for (int j = 0; j < 2; ++j) {
    const int c = j * 256 + tid;
    {  // K: linear LDS dest c*16 holds logical dbyte ((c&7)^(key&7))<<4 of row key=c>>3
      const int key = c >> 3;
      const int db = (((c & 7) ^ (key & 7)) << 4);
      ksrc[j] = (const char*)(qbase + (size_t)key * 3072 + 1024 + h * 64) + db;
      kdst[j] = (char*)Ks + c * 16;
    }
    {  // V: subtile s=c>>3 (kb=s>>2, db=s&3), chunk jj=c&7 -> key kb*4+(jj>>1), d db*16+(jj&1)*8
      const int s = c >> 3, jj = c & 7;
      const int vkey = ((s >> 2) << 2) + (jj >> 1);
      const int vd = ((s & 3) << 4) + ((jj & 1) << 3);
      vsrc[j] = (const char*)(qbase + (size_t)vkey * 3072 + 2048 + h * 64 + vd);
      vdst[j] = (char*)Vs + c * 16;
    }
  }

  f32x4 o[2][4];
  float mrow[2][4], lrow[2][4];
#pragma unroll
  for (int m = 0; m < 2; ++m)
#pragma unroll
    for (int t = 0; t < 4; ++t) o[m][t] = (f32x4){0.f, 0.f, 0.f, 0.f};
#pragma unroll
  for (int m = 0; m < 2; ++m)
#pragma unroll
    for (int i = 0; i < 4; ++i) { mrow[m][i] = -INFINITY; lrow[m][i] = 0.f; }

  // natural-b64 per-lane address: lane (l&15) owns 8-byte chunk l15*8 of each
  // subtile; tr-read returns column l15 of the [4][16] subtile.
  const uint32_t vsb = lds_off(Vs) + (uint32_t)(l15 * 8);
  const size_t tadv = (size_t)64 * 3072 * 2;  // bytes per key-tile

  for (int kt = 0; kt < 32; ++kt) {
    __syncthreads();  // prev tile's LDS reads done
    gload16(ksrc[0], kdst[0]);
    gload16(ksrc[1], kdst[1]);
    gload16(vsrc[0], vdst[0]);
    gload16(vsrc[1], vdst[1]);
    ksrc[0] += tadv; ksrc[1] += tadv; vsrc[0] += tadv; vsrc[1] += tadv;
    __syncthreads();  // staging visible (vmcnt drained at barrier)

    // ---- QK^T + online softmax per m-frag ----
#pragma unroll
    for (int m = 0; m < 2; ++m) {
      f32x4 s[4];
#pragma unroll
      for (int t = 0; t < 4; ++t) {
        s[t] = (f32x4){0.f, 0.f, 0.f, 0.f};
        const int key = t * 16 + l15;
#pragma unroll
        for (int kk = 0; kk < 2; ++kk) {
          bf16x8 kf = *(const bf16x8*)((const char*)Ks +
              ((key * 128 + kk * 64 + lg * 16) ^ ((key & 7) << 4)));
          s[t] = MFMA16(qf[m][kk], kf, s[t]);
        }
      }
      float mt[4], alpha[4];
#pragma unroll
      for (int i = 0; i < 4; ++i) {
        float v = fmaxf(fmaxf(s[0][i], s[1][i]), fmaxf(s[2][i], s[3][i]));
        v = fmaxf(v, __shfl_xor(v, 1));
        v = fmaxf(v, __shfl_xor(v, 2));
        v = fmaxf(v, __shfl_xor(v, 4));
        v = fmaxf(v, __shfl_xor(v, 8));
        const float mnew = fmaxf(mrow[m][i], v);
        alpha[i] = exp2f((mrow[m][i] - mnew) * SC);
        mrow[m][i] = mnew;
        mt[i] = mnew;
      }
      float psum[4] = {0.f, 0.f, 0.f, 0.f};
#pragma unroll
      for (int t = 0; t < 4; ++t)
#pragma unroll
        for (int i = 0; i < 4; ++i) {
          const float p = exp2f((s[t][i] - mt[i]) * SC);
          psum[i] += p;
          const int prow = m * 16 + lg * 4 + i, pcol = t * 16 + l15;
          *(bf16*)((char*)&Ps[wid][0] +
                   ((prow * 128 + pcol * 2) ^ ((prow & 7) << 4))) = (bf16)p;
        }
#pragma unroll
      for (int i = 0; i < 4; ++i) {
        float v = psum[i];
        v += __shfl_xor(v, 1);
        v += __shfl_xor(v, 2);
        v += __shfl_xor(v, 4);
        v += __shfl_xor(v, 8);
        lrow[m][i] = alpha[i] * lrow[m][i] + v;
#pragma unroll
        for (int t = 0; t < 4; ++t) o[m][t][i] *= alpha[i];
      }
    }

    // ---- O += P V ----
    bf16x8 pf[2][2];
#pragma unroll
    for (int m = 0; m < 2; ++m)
#pragma unroll
      for (int kk = 0; kk < 2; ++kk)
        pf[m][kk] = *(const bf16x8*)((const char*)&Ps[wid][0] +
            (((m * 16 + l15) * 128 + kk * 64 + lg * 16) ^ ((l15 & 7) << 4)));

#pragma unroll
    for (int t = 0; t < 4; ++t) {
      // V B-frag: keys kk*32+lg*8+[0..7], col d=t*16+l15.
      // subtile s = (kk*8 + lg*2 + sub)*4 + t; lane chunk-addr l15*8.
      const uint32_t b0 = vsb + (uint32_t)((((lg * 2) + 0) * 4 + t) * 128);
      bf16x4 v00 = tr16(b0);                  // kk=0 sub=0
      bf16x4 v01 = tr16(b0 + 512);            // kk=0 sub=1
      bf16x4 v10 = tr16(b0 + 8 * 4 * 128);    // kk=1 sub=0
      bf16x4 v11 = tr16(b0 + 8 * 4 * 128 + 512);
      asm volatile("s_waitcnt lgkmcnt(0)"
                   : "+v"(v00), "+v"(v01), "+v"(v10), "+v"(v11));
      __builtin_amdgcn_sched_barrier(0);
      bf16x8 vf0, vf1;
#pragma unroll
      for (int e = 0; e < 4; ++e) {
        vf0[e] = v00[e]; vf0[e + 4] = v01[e];
        vf1[e] = v10[e]; vf1[e + 4] = v11[e];
      }
      o[0][t] = MFMA16(pf[0][0], vf0, o[0][t]);
      o[0][t] = MFMA16(pf[0][1], vf1, o[0][t]);
      o[1][t] = MFMA16(pf[1][0], vf0, o[1][t]);
      o[1][t] = MFMA16(pf[1][1], vf1, o[1][t]);
    }
  }

  // epilogue
  bf16* ob = aout + ((size_t)b * 2048 + qblk * 128 + wid * 32) * 1024 + h * 64;
#pragma unroll
  for (int m = 0; m < 2; ++m)
#pragma unroll
    for (int i = 0; i < 4; ++i) {
      const float inv = 1.0f / lrow[m][i];
      const int row = m * 16 + lg * 4 + i;
#pragma unroll
      for (int t = 0; t < 4; ++t)
        ob[(size_t)row * 1024 + t * 16 + l15] = (bf16)(o[m][t][i] * inv);
    }
}

// ------------------------------------------------------------------ launch ---
extern "C" void kernel_launch(void* const* d_in, const int* in_sizes, int n_in,
                              void* d_out, int out_size, void* d_ws, size_t ws_size,
                              hipStream_t stream) {
  const float* query = (const float*)d_in[0];
  const float* Wqkv = (const float*)d_in[3];
  const float* bqkv = (const float*)d_in[4];
  const float* Wout = (const float*)d_in[5];
  const float* bout = (const float*)d_in[6];
  float* out = (float*)d_out;

  constexpr int M = 8192;
  constexpr int E = 1024, E3 = 3072;

  bf16* q_bf    = (bf16*)d_ws;
  bf16* wqkv_bf = q_bf + (size_t)M * E;
  bf16* wout_bf = wqkv_bf + (size_t)E3 * E;
  bf16* qkv_bf  = wout_bf + (size_t)E * E;
  bf16* aout_bf = qkv_bf + (size_t)M * E3;

  cvt_f32_bf16<<<(M * E / 4 + 255) / 256, 256, 0, stream>>>(query, q_bf, M * E / 4);
  cvt_f32_bf16<<<(E3 * E / 4 + 255) / 256, 256, 0, stream>>>(Wqkv, wqkv_bf, E3 * E / 4);
  cvt_f32_bf16<<<(E * E / 4 + 255) / 256, 256, 0, stream>>>(Wout, wout_bf, E * E / 4);

  gemm_bt<bf16><<<dim3(E3 / 128, M / 128), 256, 0, stream>>>(q_bf, wqkv_bf, bqkv, qkv_bf, M, E3, E);
  attn_fwd<<<dim3(16, 16, 4), 256, 0, stream>>>(qkv_bf, aout_bf);
  gemm_bt<float><<<dim3(E / 128, M / 128), 256, 0, stream>>>(aout_bf, wout_bf, bout, out, M, E, E);
}

// Round 4
// 345.770 us; speedup vs baseline: 1.5345x; 1.5345x over previous
//
#include <hip/hip_runtime.h>
#include <stdint.h>

// ---------------------------------------------------------------------------
// MultiHeadAttention: out = proj(attn(qkv_proj(query)))
// B=4 S=2048 E=1024 H=16 HD=64.  scale = 1/sqrt(E) = 1/32.
// cvt(fp32->bf16) -> GEMM1(bias, bf16 out) -> flash-attn -> GEMM2(bias, f32 out)
// ---------------------------------------------------------------------------

typedef __bf16 bf16;
typedef __bf16 bf16x8 __attribute__((ext_vector_type(8)));
typedef __bf16 bf16x4 __attribute__((ext_vector_type(4)));
typedef float  f32x4  __attribute__((ext_vector_type(4)));

#define MFMA16(a, b, c) __builtin_amdgcn_mfma_f32_16x16x32_bf16((a), (b), (c), 0, 0, 0)

__device__ __forceinline__ void gload16(const void* g, void* l) {
  __builtin_amdgcn_global_load_lds(
      (const __attribute__((address_space(1))) void*)g,
      (__attribute__((address_space(3))) void*)l, 16, 0, 0);
}

__device__ __forceinline__ uint32_t lds_off(const void* p) {
  return (uint32_t)(uintptr_t)(__attribute__((address_space(3))) const void*)p;
}

// hardware transpose read, natural-b64 addressing: lane supplies its own
// 8-byte-chunk address within a [4][16]-bf16 subtile; HW returns the COLUMN
// (addr>>3)&15 of that subtile.
__device__ __forceinline__ bf16x4 tr16(uint32_t off) {
  bf16x4 d;
  asm volatile("ds_read_b64_tr_b16 %0, %1" : "=&v"(d) : "v"(off));
  return d;
}

// ---------------------------------------------------------------- convert ---
__global__ __launch_bounds__(256) void cvt_f32_bf16(const float* __restrict__ in,
                                                    bf16* __restrict__ out, int n4) {
  int i = blockIdx.x * 256 + threadIdx.x;
  if (i >= n4) return;
  const float4 v = ((const float4*)in)[i];
  bf16x4 o;
  o[0] = (bf16)v.x; o[1] = (bf16)v.y; o[2] = (bf16)v.z; o[3] = (bf16)v.w;
  ((bf16x4*)out)[i] = o;
}

// ------------------------------------------------------------------- GEMM ---
// C[M][N] = A[M][K] @ Bt[N][K]^T + bias[N].  m97 structure (unchanged).
template <typename OutT>
__global__ __launch_bounds__(256, 2) void gemm_bt(const bf16* __restrict__ A,
                                                  const bf16* __restrict__ Bt,
                                                  const float* __restrict__ bias,
                                                  OutT* __restrict__ C,
                                                  int M, int N, int K) {
  __shared__ bf16 As[128 * 32];
  __shared__ bf16 Bs[128 * 32];
  const int tid = threadIdx.x;
  const int lane = tid & 63, wid = tid >> 6;
  const int l15 = lane & 15, lg = lane >> 4;
  const int wr = wid >> 1, wc = wid & 1;
  const int row0 = blockIdx.y * 128, col0 = blockIdx.x * 128;

  f32x4 acc[4][4];
#pragma unroll
  for (int m = 0; m < 4; ++m)
#pragma unroll
    for (int n = 0; n < 4; ++n) acc[m][n] = (f32x4){0.f, 0.f, 0.f, 0.f};

  for (int k0 = 0; k0 < K; k0 += 32) {
    __syncthreads();
#pragma unroll
    for (int j = 0; j < 2; ++j) {
      const int c = j * 256 + tid;
      const int r = c >> 2, cb = (c & 3) << 4;
      gload16((const char*)(A + (size_t)(row0 + r) * K + k0) + cb, (char*)As + c * 16);
      gload16((const char*)(Bt + (size_t)(col0 + r) * K + k0) + cb, (char*)Bs + c * 16);
    }
    __syncthreads();

    bf16x8 af[4], bfr[4];
#pragma unroll
    for (int m = 0; m < 4; ++m)
      af[m] = *(const bf16x8*)(As + ((wr * 64 + m * 16 + l15) << 5) + lg * 8);
#pragma unroll
    for (int n = 0; n < 4; ++n)
      bfr[n] = *(const bf16x8*)(Bs + ((wc * 64 + n * 16 + l15) << 5) + lg * 8);
#pragma unroll
    for (int m = 0; m < 4; ++m)
#pragma unroll
      for (int n = 0; n < 4; ++n) acc[m][n] = MFMA16(af[m], bfr[n], acc[m][n]);
  }

#pragma unroll
  for (int m = 0; m < 4; ++m) {
    const int grow0 = row0 + wr * 64 + m * 16 + lg * 4;
#pragma unroll
    for (int n = 0; n < 4; ++n) {
      const int gcol = col0 + wc * 64 + n * 16 + l15;
      const float bv = bias[gcol];
#pragma unroll
      for (int i = 0; i < 4; ++i)
        C[(size_t)(grow0 + i) * N + gcol] = (OutT)(acc[m][n][i] + bv);
    }
  }
}

// -------------------------------------------------------------- attention ---
// Flat grid 1024, XCD-clustered swizzle: all 16 q-blocks of one (b,h) group
// land on one XCD (8 groups/XCD -> 4MB K/V fits that XCD's L2).
// 2-phase prefetch: double-buffered K/V tiles, next tile's global_load_lds
// issued BEFORE computing current; counted s_waitcnt vmcnt(4) + raw barriers
// keep the prefetch in flight across the barrier (no vmcnt(0) drain mid-loop).
__global__ __launch_bounds__(256, 3) void attn_fwd(const bf16* __restrict__ qkv,
                                                   bf16* __restrict__ aout) {
  __shared__ bf16 Ks[2][64 * 64];
  __shared__ bf16 Vs[2][64 * 64];
  __shared__ bf16 Ps[4][32 * 64];

  // XCD-clustered block swizzle (perf-only; any block->XCD mapping is correct)
  const int bid = blockIdx.x;
  const int xcd = bid & 7, slot = bid >> 3;
  const int g = xcd + 8 * (slot >> 4);   // 0..63 = (b,h) group
  const int qblk = slot & 15;
  const int h = g & 15, b = g >> 4;

  const int tid = threadIdx.x, wid = tid >> 6, lane = tid & 63;
  const int l15 = lane & 15, lg = lane >> 4;
  const bf16* qbase = qkv + (size_t)b * 2048 * 3072;
  constexpr float SC = 0.045084220f;  // (1/32) * log2(e)

  // Q fragments: rows qblk*128 + wid*32 + m*16 + l15, k = kk*32 + lg*8
  bf16x8 qf[2][2];
  {
    const bf16* qp = qbase + (size_t)(qblk * 128 + wid * 32 + l15) * 3072 + h * 64 + lg * 8;
    qf[0][0] = *(const bf16x8*)(qp);
    qf[0][1] = *(const bf16x8*)(qp + 32);
    qf[1][0] = *(const bf16x8*)(qp + 16 * 3072);
    qf[1][1] = *(const bf16x8*)(qp + 16 * 3072 + 32);
  }

  // staging sources (tile 0) and LDS dest offsets: 2 K + 2 V chunks/thread
  const char* ksrc[2]; const char* vsrc[2];
  int kdo[2], vdo[2];
#pragma unroll
  for (int j = 0; j < 2; ++j) {
    const int c = j * 256 + tid;
    {  // K: linear dest c*16 holds logical dbyte ((c&7)^(key&7))<<4 of row key=c>>3
      const int key = c >> 3;
      const int db = (((c & 7) ^ (key & 7)) << 4);
      ksrc[j] = (const char*)(qbase + (size_t)key * 3072 + 1024 + h * 64) + db;
      kdo[j] = c * 16;
    }
    {  // V: subtile s=c>>3 (kb=s>>2, db=s&3), chunk jj=c&7
      const int s = c >> 3, jj = c & 7;
      const int vkey = ((s >> 2) << 2) + (jj >> 1);
      const int vd = ((s & 3) << 4) + ((jj & 1) << 3);
      vsrc[j] = (const char*)(qbase + (size_t)vkey * 3072 + 2048 + h * 64 + vd);
      vdo[j] = c * 16;
    }
  }
  const size_t tadv = (size_t)64 * 3072 * 2;  // bytes per key-tile

  f32x4 o[2][4];
  float mrow[2][4], lrow[2][4];
#pragma unroll
  for (int m = 0; m < 2; ++m)
#pragma unroll
    for (int t = 0; t < 4; ++t) o[m][t] = (f32x4){0.f, 0.f, 0.f, 0.f};
#pragma unroll
  for (int m = 0; m < 2; ++m)
#pragma unroll
    for (int i = 0; i < 4; ++i) { mrow[m][i] = -INFINITY; lrow[m][i] = 0.f; }

  const uint32_t vsb0 = lds_off(&Vs[0][0]) + (uint32_t)(l15 * 8);

  // prologue: stage tile 0 into buf 0
  {
    gload16(ksrc[0], (char*)&Ks[0][0] + kdo[0]);
    gload16(ksrc[1], (char*)&Ks[0][0] + kdo[1]);
    gload16(vsrc[0], (char*)&Vs[0][0] + vdo[0]);
    gload16(vsrc[1], (char*)&Vs[0][0] + vdo[1]);
  }

  for (int kt = 0; kt < 32; ++kt) {
    const int cur = kt & 1;
    if (kt < 31) {  // issue next tile into other buffer, keep it in flight
      const size_t off = (size_t)(kt + 1) * tadv;
      char* kb = (char*)&Ks[cur ^ 1][0];
      char* vb = (char*)&Vs[cur ^ 1][0];
      gload16(ksrc[0] + off, kb + kdo[0]);
      gload16(ksrc[1] + off, kb + kdo[1]);
      gload16(vsrc[0] + off, vb + vdo[0]);
      gload16(vsrc[1] + off, vb + vdo[1]);
      __builtin_amdgcn_sched_barrier(0);
      asm volatile("s_waitcnt vmcnt(4)" ::: "memory");  // current tile landed
    } else {
      __builtin_amdgcn_sched_barrier(0);
      asm volatile("s_waitcnt vmcnt(0)" ::: "memory");
    }
    __builtin_amdgcn_s_barrier();  // all waves' current tile in LDS
    __builtin_amdgcn_sched_barrier(0);

    const char* ksb = (const char*)&Ks[cur][0];
    const uint32_t vbb = vsb0 + (uint32_t)(cur * 8192);

    // ---- QK^T + online softmax per m-frag ----
#pragma unroll
    for (int m = 0; m < 2; ++m) {
      f32x4 s[4];
      __builtin_amdgcn_s_setprio(1);
#pragma unroll
      for (int t = 0; t < 4; ++t) {
        s[t] = (f32x4){0.f, 0.f, 0.f, 0.f};
        const int key = t * 16 + l15;
#pragma unroll
        for (int kk = 0; kk < 2; ++kk) {
          bf16x8 kf = *(const bf16x8*)(ksb +
              ((key * 128 + kk * 64 + lg * 16) ^ ((key & 7) << 4)));
          s[t] = MFMA16(qf[m][kk], kf, s[t]);
        }
      }
      __builtin_amdgcn_s_setprio(0);
      float mt[4], alpha[4];
#pragma unroll
      for (int i = 0; i < 4; ++i) {
        float v = fmaxf(fmaxf(s[0][i], s[1][i]), fmaxf(s[2][i], s[3][i]));
        v = fmaxf(v, __shfl_xor(v, 1));
        v = fmaxf(v, __shfl_xor(v, 2));
        v = fmaxf(v, __shfl_xor(v, 4));
        v = fmaxf(v, __shfl_xor(v, 8));
        const float mnew = fmaxf(mrow[m][i], v);
        alpha[i] = exp2f((mrow[m][i] - mnew) * SC);
        mrow[m][i] = mnew;
        mt[i] = mnew;
      }
      float psum[4] = {0.f, 0.f, 0.f, 0.f};
#pragma unroll
      for (int t = 0; t < 4; ++t)
#pragma unroll
        for (int i = 0; i < 4; ++i) {
          const float p = exp2f((s[t][i] - mt[i]) * SC);
          psum[i] += p;
          const int prow = m * 16 + lg * 4 + i, pcol = t * 16 + l15;
          *(bf16*)((char*)&Ps[wid][0] +
                   ((prow * 128 + pcol * 2) ^ ((prow & 7) << 4))) = (bf16)p;
        }
#pragma unroll
      for (int i = 0; i < 4; ++i) {
        float v = psum[i];
        v += __shfl_xor(v, 1);
        v += __shfl_xor(v, 2);
        v += __shfl_xor(v, 4);
        v += __shfl_xor(v, 8);
        lrow[m][i] = alpha[i] * lrow[m][i] + v;
#pragma unroll
        for (int t = 0; t < 4; ++t) o[m][t][i] *= alpha[i];
      }
    }

    // ---- O += P V ----
    bf16x8 pf[2][2];
#pragma unroll
    for (int m = 0; m < 2; ++m)
#pragma unroll
      for (int kk = 0; kk < 2; ++kk)
        pf[m][kk] = *(const bf16x8*)((const char*)&Ps[wid][0] +
            (((m * 16 + l15) * 128 + kk * 64 + lg * 16) ^ ((l15 & 7) << 4)));

#pragma unroll
    for (int t = 0; t < 4; ++t) {
      // V B-frag: keys kk*32+lg*8+[0..7], col d=t*16+l15.
      const uint32_t b0 = vbb + (uint32_t)((((lg * 2) + 0) * 4 + t) * 128);
      bf16x4 v00 = tr16(b0);                  // kk=0 sub=0
      bf16x4 v01 = tr16(b0 + 512);            // kk=0 sub=1
      bf16x4 v10 = tr16(b0 + 8 * 4 * 128);    // kk=1 sub=0
      bf16x4 v11 = tr16(b0 + 8 * 4 * 128 + 512);
      asm volatile("s_waitcnt lgkmcnt(0)"
                   : "+v"(v00), "+v"(v01), "+v"(v10), "+v"(v11));
      __builtin_amdgcn_sched_barrier(0);
      bf16x8 vf0, vf1;
#pragma unroll
      for (int e = 0; e < 4; ++e) {
        vf0[e] = v00[e]; vf0[e + 4] = v01[e];
        vf1[e] = v10[e]; vf1[e + 4] = v11[e];
      }
      __builtin_amdgcn_s_setprio(1);
      o[0][t] = MFMA16(pf[0][0], vf0, o[0][t]);
      o[0][t] = MFMA16(pf[0][1], vf1, o[0][t]);
      o[1][t] = MFMA16(pf[1][0], vf0, o[1][t]);
      o[1][t] = MFMA16(pf[1][1], vf1, o[1][t]);
      __builtin_amdgcn_s_setprio(0);
    }
    __builtin_amdgcn_sched_barrier(0);
    __builtin_amdgcn_s_barrier();  // LDS reads done; next iter may overwrite
  }

  // epilogue
  bf16* ob = aout + ((size_t)b * 2048 + qblk * 128 + wid * 32) * 1024 + h * 64;
#pragma unroll
  for (int m = 0; m < 2; ++m)
#pragma unroll
    for (int i = 0; i < 4; ++i) {
      const float inv = 1.0f / lrow[m][i];
      const int row = m * 16 + lg * 4 + i;
#pragma unroll
      for (int t = 0; t < 4; ++t)
        ob[(size_t)row * 1024 + t * 16 + l15] = (bf16)(o[m][t][i] * inv);
    }
}

// ------------------------------------------------------------------ launch ---
extern "C" void kernel_launch(void* const* d_in, const int* in_sizes, int n_in,
                              void* d_out, int out_size, void* d_ws, size_t ws_size,
                              hipStream_t stream) {
  const float* query = (const float*)d_in[0];
  const float* Wqkv = (const float*)d_in[3];
  const float* bqkv = (const float*)d_in[4];
  const float* Wout = (const float*)d_in[5];
  const float* bout = (const float*)d_in[6];
  float* out = (float*)d_out;

  constexpr int M = 8192;
  constexpr int E = 1024, E3 = 3072;

  bf16* q_bf    = (bf16*)d_ws;
  bf16* wqkv_bf = q_bf + (size_t)M * E;
  bf16* wout_bf = wqkv_bf + (size_t)E3 * E;
  bf16* qkv_bf  = wout_bf + (size_t)E * E;
  bf16* aout_bf = qkv_bf + (size_t)M * E3;

  cvt_f32_bf16<<<(M * E / 4 + 255) / 256, 256, 0, stream>>>(query, q_bf, M * E / 4);
  cvt_f32_bf16<<<(E3 * E / 4 + 255) / 256, 256, 0, stream>>>(Wqkv, wqkv_bf, E3 * E / 4);
  cvt_f32_bf16<<<(E * E / 4 + 255) / 256, 256, 0, stream>>>(Wout, wout_bf, E * E / 4);

  gemm_bt<bf16><<<dim3(E3 / 128, M / 128), 256, 0, stream>>>(q_bf, wqkv_bf, bqkv, qkv_bf, M, E3, E);
  attn_fwd<<<1024, 256, 0, stream>>>(qkv_bf, aout_bf);
  gemm_bt<float><<<dim3(E / 128, M / 128), 256, 0, stream>>>(aout_bf, wout_bf, bout, out, M, E, E);
}

// Round 5
// 210.209 us; speedup vs baseline: 2.5240x; 1.6449x over previous
//
#include <hip/hip_runtime.h>
#include <stdint.h>

// ---------------------------------------------------------------------------
// MultiHeadAttention: out = proj(attn(qkv_proj(query)))
// B=4 S=2048 E=1024 H=16 HD=64.  scale = 1/sqrt(E) = 1/32.
// cvt(fp32->bf16) -> GEMM1(bias, bf16 out) -> flash-attn -> GEMM2(bias, f32 out)
// ---------------------------------------------------------------------------

typedef __bf16 bf16;
typedef __bf16 bf16x8 __attribute__((ext_vector_type(8)));
typedef __bf16 bf16x4 __attribute__((ext_vector_type(4)));
typedef float  f32x4  __attribute__((ext_vector_type(4)));
typedef float  f32x16 __attribute__((ext_vector_type(16)));
typedef unsigned u32x4 __attribute__((ext_vector_type(4)));

#define MFMA16(a, b, c) __builtin_amdgcn_mfma_f32_16x16x32_bf16((a), (b), (c), 0, 0, 0)
#define MFMA32(a, b, c) __builtin_amdgcn_mfma_f32_32x32x16_bf16((a), (b), (c), 0, 0, 0)

__device__ __forceinline__ void gload16(const void* g, void* l) {
  __builtin_amdgcn_global_load_lds(
      (const __attribute__((address_space(1))) void*)g,
      (__attribute__((address_space(3))) void*)l, 16, 0, 0);
}

__device__ __forceinline__ uint32_t lds_off(const void* p) {
  return (uint32_t)(uintptr_t)(__attribute__((address_space(3))) const void*)p;
}

// hardware transpose read, natural-b64 addressing: lane supplies its own
// 8-byte-chunk address within a [4key][16d] bf16 subtile; HW returns the
// COLUMN (addr>>3)&15 of subtile addr>>7 (verified R3).
__device__ __forceinline__ bf16x4 tr16(uint32_t off) {
  bf16x4 d;
  asm volatile("ds_read_b64_tr_b16 %0, %1" : "=&v"(d) : "v"(off));
  return d;
}

// ---------------------------------------------------------------- convert ---
__global__ __launch_bounds__(256) void cvt_f32_bf16(const float* __restrict__ in,
                                                    bf16* __restrict__ out, int n4) {
  int i = blockIdx.x * 256 + threadIdx.x;
  if (i >= n4) return;
  const float4 v = ((const float4*)in)[i];
  bf16x4 o;
  o[0] = (bf16)v.x; o[1] = (bf16)v.y; o[2] = (bf16)v.z; o[3] = (bf16)v.w;
  ((bf16x4*)out)[i] = o;
}

// ------------------------------------------------------------------- GEMM ---
// C[M][N] = A[M][K] @ Bt[N][K]^T + bias[N].  m97 structure (unchanged).
template <typename OutT>
__global__ __launch_bounds__(256, 2) void gemm_bt(const bf16* __restrict__ A,
                                                  const bf16* __restrict__ Bt,
                                                  const float* __restrict__ bias,
                                                  OutT* __restrict__ C,
                                                  int M, int N, int K) {
  __shared__ bf16 As[128 * 32];
  __shared__ bf16 Bs[128 * 32];
  const int tid = threadIdx.x;
  const int lane = tid & 63, wid = tid >> 6;
  const int l15 = lane & 15, lg = lane >> 4;
  const int wr = wid >> 1, wc = wid & 1;
  const int row0 = blockIdx.y * 128, col0 = blockIdx.x * 128;

  f32x4 acc[4][4];
#pragma unroll
  for (int m = 0; m < 4; ++m)
#pragma unroll
    for (int n = 0; n < 4; ++n) acc[m][n] = (f32x4){0.f, 0.f, 0.f, 0.f};

  for (int k0 = 0; k0 < K; k0 += 32) {
    __syncthreads();
#pragma unroll
    for (int j = 0; j < 2; ++j) {
      const int c = j * 256 + tid;
      const int r = c >> 2, cb = (c & 3) << 4;
      gload16((const char*)(A + (size_t)(row0 + r) * K + k0) + cb, (char*)As + c * 16);
      gload16((const char*)(Bt + (size_t)(col0 + r) * K + k0) + cb, (char*)Bs + c * 16);
    }
    __syncthreads();

    bf16x8 af[4], bfr[4];
#pragma unroll
    for (int m = 0; m < 4; ++m)
      af[m] = *(const bf16x8*)(As + ((wr * 64 + m * 16 + l15) << 5) + lg * 8);
#pragma unroll
    for (int n = 0; n < 4; ++n)
      bfr[n] = *(const bf16x8*)(Bs + ((wc * 64 + n * 16 + l15) << 5) + lg * 8);
#pragma unroll
    for (int m = 0; m < 4; ++m)
#pragma unroll
      for (int n = 0; n < 4; ++n) acc[m][n] = MFMA16(af[m], bfr[n], acc[m][n]);
  }

#pragma unroll
  for (int m = 0; m < 4; ++m) {
    const int grow0 = row0 + wr * 64 + m * 16 + lg * 4;
#pragma unroll
    for (int n = 0; n < 4; ++n) {
      const int gcol = col0 + wc * 64 + n * 16 + l15;
      const float bv = bias[gcol];
#pragma unroll
      for (int i = 0; i < 4; ++i)
        C[(size_t)(grow0 + i) * N + gcol] = (OutT)(acc[m][n][i] + bv);
    }
  }
}

// -------------------------------------------------------------- attention ---
// Flat grid 1024, XCD-clustered swizzle (R4).  32x32x16 MFMA, swapped QK^T
// (S^T = K.Q^T -> each lane owns one q-row, keys in-lane), in-register
// softmax with defer-max (THR), cvt_pk+permlane32_swap P->A-frag assembly
// (no P LDS).  K tile XOR-swizzled via pre-swizzled gload source; V subtiled
// [key/4][d/16][4][16] read with ds_read_b64_tr_b16.  2-phase prefetch with
// counted vmcnt(4).
__global__ __launch_bounds__(256, 4) void attn_fwd(const bf16* __restrict__ qkv,
                                                   bf16* __restrict__ aout) {
  __shared__ bf16 Ks[2][64 * 64];
  __shared__ bf16 Vs[2][64 * 64];
  __shared__ float bc[4][32];

  const int bid = blockIdx.x;
  const int xcd = bid & 7, slot = bid >> 3;
  const int g = xcd + 8 * (slot >> 4);   // (b,h) group: 16 q-blocks on 1 XCD
  const int qblk = slot & 15;
  const int h = g & 15, b = g >> 4;

  const int tid = threadIdx.x, wid = tid >> 6, lane = tid & 63;
  const int l31 = lane & 31, hh = lane >> 5, l15 = lane & 15;
  const int b4 = (lane >> 4) & 1;
  const bf16* qbase = qkv + (size_t)b * 2048 * 3072;
  constexpr float SC = 0.045084220f;  // (1/32) * log2(e)

  // Q B-frags: qf[k2] = Q[qrow = wid*32+l31][d = k2*16 + hh*8 + 0..7]
  bf16x8 qf[4];
  {
    const bf16* qp = qbase + (size_t)(qblk * 128 + wid * 32 + l31) * 3072 + h * 64 + hh * 8;
    qf[0] = *(const bf16x8*)(qp);
    qf[1] = *(const bf16x8*)(qp + 16);
    qf[2] = *(const bf16x8*)(qp + 32);
    qf[3] = *(const bf16x8*)(qp + 48);
  }

  // staging sources (tile 0) and LDS dest offsets: 2 K + 2 V chunks/thread
  const char* ksrc[2]; const char* vsrc[2];
  int kdo[2], vdo[2];
#pragma unroll
  for (int j = 0; j < 2; ++j) {
    const int c = j * 256 + tid;
    {  // K: linear dest c*16 holds logical dbyte ((c&7)^(key&7))<<4 of row key=c>>3
      const int key = c >> 3;
      const int db = (((c & 7) ^ (key & 7)) << 4);
      ksrc[j] = (const char*)(qbase + (size_t)key * 3072 + 1024 + h * 64) + db;
      kdo[j] = c * 16;
    }
    {  // V: subtile s=c>>3 (kb4=s>>2, db=s&3), chunk jj=c&7
      const int s = c >> 3, jj = c & 7;
      const int vkey = ((s >> 2) << 2) + (jj >> 1);
      const int vd = ((s & 3) << 4) + ((jj & 1) << 3);
      vsrc[j] = (const char*)(qbase + (size_t)vkey * 3072 + 2048 + h * 64 + vd);
      vdo[j] = c * 16;
    }
  }
  const size_t tadv = (size_t)64 * 3072 * 2;  // bytes per key-tile

  f32x16 o0, o1;
#pragma unroll
  for (int i = 0; i < 16; ++i) { o0[i] = 0.f; o1[i] = 0.f; }
  float m = 0.f, lrow = 0.f;

  const uint32_t vsb0 = lds_off(&Vs[0][0]) + (uint32_t)(l15 * 8);

  // prologue: stage tile 0 into buf 0
  gload16(ksrc[0], (char*)&Ks[0][0] + kdo[0]);
  gload16(ksrc[1], (char*)&Ks[0][0] + kdo[1]);
  gload16(vsrc[0], (char*)&Vs[0][0] + vdo[0]);
  gload16(vsrc[1], (char*)&Vs[0][0] + vdo[1]);

  for (int kt = 0; kt < 32; ++kt) {
    const int cur = kt & 1;
    if (kt < 31) {  // issue next tile into other buffer, keep it in flight
      const size_t off = (size_t)(kt + 1) * tadv;
      char* kb = (char*)&Ks[cur ^ 1][0];
      char* vb = (char*)&Vs[cur ^ 1][0];
      gload16(ksrc[0] + off, kb + kdo[0]);
      gload16(ksrc[1] + off, kb + kdo[1]);
      gload16(vsrc[0] + off, vb + vdo[0]);
      gload16(vsrc[1] + off, vb + vdo[1]);
      __builtin_amdgcn_sched_barrier(0);
      asm volatile("s_waitcnt vmcnt(4)" ::: "memory");  // current tile landed
    } else {
      __builtin_amdgcn_sched_barrier(0);
      asm volatile("s_waitcnt vmcnt(0)" ::: "memory");
    }
    __builtin_amdgcn_s_barrier();
    __builtin_amdgcn_sched_barrier(0);

    const char* ksb = (const char*)&Ks[cur][0];
    const uint32_t vbb = vsb0 + (uint32_t)(cur * 8192);

    // ---- S^T = K.Q^T : A-frag = K rows (from LDS), B-frag = Q (regs) ----
    f32x16 st0, st1;
#pragma unroll
    for (int i = 0; i < 16; ++i) { st0[i] = 0.f; st1[i] = 0.f; }
    __builtin_amdgcn_s_setprio(1);
#pragma unroll
    for (int k2 = 0; k2 < 4; ++k2) {
      const int dby = k2 * 32 + hh * 16;
      bf16x8 kf0 = *(const bf16x8*)(ksb + ((l31 * 128 + dby) ^ ((l31 & 7) << 4)));
      st0 = MFMA32(kf0, qf[k2], st0);
      bf16x8 kf1 = *(const bf16x8*)(ksb + (((l31 + 32) * 128 + dby) ^ ((l31 & 7) << 4)));
      st1 = MFMA32(kf1, qf[k2], st1);
    }
    __builtin_amdgcn_s_setprio(0);

    // ---- in-lane softmax for q-row l31 (keys: 32 in-lane + 32 in lane^32) --
    float pm = -3.0e38f;
#pragma unroll
    for (int i = 0; i < 16; ++i) pm = fmaxf(pm, fmaxf(st0[i], st1[i]));
    pm = fmaxf(pm, __shfl_xor(pm, 32));

    if (!__all(pm - m <= 48.0f)) {  // defer-max slow path (rare)
      const float mn = fmaxf(m, pm);
      const float alpha = __builtin_amdgcn_exp2f((m - mn) * SC);
      m = mn;
      lrow *= alpha;
      if (lane < 32) bc[wid][l31] = alpha;
#pragma unroll
      for (int r = 0; r < 16; ++r) {
        const float av = bc[wid][(r & 3) + 8 * (r >> 2) + 4 * hh];
        o0[r] *= av; o1[r] *= av;
      }
    }

    const float msc = m * SC;
    float ps = 0.f;
#pragma unroll
    for (int i = 0; i < 16; ++i) {
      st0[i] = __builtin_amdgcn_exp2f(fmaf(st0[i], SC, -msc));
      st1[i] = __builtin_amdgcn_exp2f(fmaf(st1[i], SC, -msc));
      ps += st0[i] + st1[i];
    }
    ps += __shfl_xor(ps, 32);
    lrow += ps;

    // ---- P -> bf16 A-frags: cvt_pk pairs, then permlane32_swap ----
    uint32_t w[16];
#pragma unroll
    for (int j = 0; j < 8; ++j) {
      asm("v_cvt_pk_bf16_f32 %0, %1, %2" : "=v"(w[j]) : "v"(st0[2 * j]), "v"(st0[2 * j + 1]));
      asm("v_cvt_pk_bf16_f32 %0, %1, %2" : "=v"(w[8 + j]) : "v"(st1[2 * j]), "v"(st1[2 * j + 1]));
    }
#pragma unroll
    for (int g2 = 0; g2 < 4; ++g2) {
      asm volatile("v_permlane32_swap_b32 %0, %1" : "+v"(w[4 * g2]), "+v"(w[4 * g2 + 2]));
      asm volatile("v_permlane32_swap_b32 %0, %1" : "+v"(w[4 * g2 + 1]), "+v"(w[4 * g2 + 3]));
    }
    bf16x8 pf[4];
#pragma unroll
    for (int k2 = 0; k2 < 4; ++k2) {
      u32x4 t;
      t[0] = w[4 * k2]; t[1] = w[4 * k2 + 1]; t[2] = w[4 * k2 + 2]; t[3] = w[4 * k2 + 3];
      pf[k2] = __builtin_bit_cast(bf16x8, t);
    }

    // ---- O += P.V : B-frag = V[key = k2*16+hh*8+e][d = db*32+l31] ----
#pragma unroll
    for (int db = 0; db < 2; ++db) {
      bf16x4 va[4], vb2[4];
#pragma unroll
      for (int k2 = 0; k2 < 4; ++k2) {
        const uint32_t s0 = (uint32_t)((((k2 * 4 + hh * 2) * 4) + db * 2 + b4) * 128);
        va[k2]  = tr16(vbb + s0);
        vb2[k2] = tr16(vbb + s0 + 512);
      }
      asm volatile("s_waitcnt lgkmcnt(0)" ::: "memory");
      __builtin_amdgcn_sched_barrier(0);
      __builtin_amdgcn_s_setprio(1);
#pragma unroll
      for (int k2 = 0; k2 < 4; ++k2) {
        bf16x8 vf;
#pragma unroll
        for (int e = 0; e < 4; ++e) { vf[e] = va[k2][e]; vf[e + 4] = vb2[k2][e]; }
        if (db == 0) o0 = MFMA32(pf[k2], vf, o0);
        else         o1 = MFMA32(pf[k2], vf, o1);
      }
      __builtin_amdgcn_s_setprio(0);
    }
    __builtin_amdgcn_sched_barrier(0);
    __builtin_amdgcn_s_barrier();  // LDS reads done; next iter may overwrite
  }

  // ---- epilogue: broadcast 1/l by q-row, store D-layout ----
  if (lane < 32) bc[wid][l31] = 1.0f / lrow;
  bf16* ob = aout + ((size_t)b * 2048 + qblk * 128 + wid * 32) * 1024 + h * 64;
#pragma unroll
  for (int r = 0; r < 16; ++r) {
    const int row = (r & 3) + 8 * (r >> 2) + 4 * hh;
    const float inv = bc[wid][row];
    ob[(size_t)row * 1024 + l31]      = (bf16)(o0[r] * inv);
    ob[(size_t)row * 1024 + 32 + l31] = (bf16)(o1[r] * inv);
  }
}

// ------------------------------------------------------------------ launch ---
extern "C" void kernel_launch(void* const* d_in, const int* in_sizes, int n_in,
                              void* d_out, int out_size, void* d_ws, size_t ws_size,
                              hipStream_t stream) {
  const float* query = (const float*)d_in[0];
  const float* Wqkv = (const float*)d_in[3];
  const float* bqkv = (const float*)d_in[4];
  const float* Wout = (const float*)d_in[5];
  const float* bout = (const float*)d_in[6];
  float* out = (float*)d_out;

  constexpr int M = 8192;
  constexpr int E = 1024, E3 = 3072;

  bf16* q_bf    = (bf16*)d_ws;
  bf16* wqkv_bf = q_bf + (size_t)M * E;
  bf16* wout_bf = wqkv_bf + (size_t)E3 * E;
  bf16* qkv_bf  = wout_bf + (size_t)E * E;
  bf16* aout_bf = qkv_bf + (size_t)M * E3;

  cvt_f32_bf16<<<(M * E / 4 + 255) / 256, 256, 0, stream>>>(query, q_bf, M * E / 4);
  cvt_f32_bf16<<<(E3 * E / 4 + 255) / 256, 256, 0, stream>>>(Wqkv, wqkv_bf, E3 * E / 4);
  cvt_f32_bf16<<<(E * E / 4 + 255) / 256, 256, 0, stream>>>(Wout, wout_bf, E * E / 4);

  gemm_bt<bf16><<<dim3(E3 / 128, M / 128), 256, 0, stream>>>(q_bf, wqkv_bf, bqkv, qkv_bf, M, E3, E);
  attn_fwd<<<1024, 256, 0, stream>>>(qkv_bf, aout_bf);
  gemm_bt<float><<<dim3(E / 128, M / 128), 256, 0, stream>>>(aout_bf, wout_bf, bout, out, M, E, E);
}